// Round 16
// baseline (157.186 us; speedup 1.0000x reference)
//
#include <hip/hip_runtime.h>

#define NGRAPH 512
#define NPG    256
#define KPG    128
#define NN     (NGRAPH * NPG)   // 131072 nodes
#define KK     (NGRAPH * KPG)   // 65536 kept nodes
#define NE     4194304          // edges
#define DF     128
#define DE     16

#define SBLK   256              // threads per edge block
#define EPB    1024             // edges per tile (4 per thread)
#define NTILE  (NE / EPB)       // 4096 tiles

typedef float vf4 __attribute__((ext_vector_type(4)));
typedef int   vi4 __attribute__((ext_vector_type(4)));

// output layout (float32 elements, concatenated in reference return order)
#define OUT_X     0ull
#define OUT_EI    ((size_t)KK * DF)                 // 8388608
#define OUT_ATTR  (OUT_EI + 2ull * NE)              // 16777216
#define OUT_BATCH (OUT_ATTR + (size_t)NE * DE)      // 83886080
#define OUT_PERM  (OUT_BATCH + KK)
#define OUT_W     (OUT_PERM + KK)

// --- 1. fused score + top-k + gather-scale + rank8 table -----------------
__global__ void __launch_bounds__(NPG)
topk_all_kernel(const float* __restrict__ x,
                const float* __restrict__ W,
                const float* __restrict__ b,
                unsigned char* __restrict__ rank8,
                float* __restrict__ out) {
    __shared__ __align__(16) float s[NPG];
    __shared__ int   sel[KPG];      // rank -> local node id
    __shared__ float selw[KPG];     // rank -> score
    int g = blockIdx.x, t = threadIdx.x;
    int l32 = t & 31, grp = t >> 5;
    float bias = b[0];

    // scores: 8 rows in flight (32 lanes x float4), 32 iters covers 256 rows
    float4 wv = ((const float4*)W)[l32];
    #pragma unroll 4
    for (int it = 0; it < NPG / 8; it++) {
        int r = it * 8 + grp;
        float4 xv = ((const float4*)(x + ((size_t)g * NPG + r) * DF))[l32];
        float sum = xv.x * wv.x + xv.y * wv.y + xv.z * wv.z + xv.w * wv.w;
        #pragma unroll
        for (int off = 16; off > 0; off >>= 1) sum += __shfl_down(sum, off, 32);
        if (l32 == 0) s[r] = sum + bias;
    }
    __syncthreads();
    float my = s[t];
    // rank = #{j: s[j] > my} + #{j < t: s[j] == my}
    const float4* s4p = (const float4*)s;
    int rank = 0;
    #pragma unroll 8
    for (int j4 = 0; j4 < NPG / 4; j4++) {
        float4 o = s4p[j4];
        rank += (o.x > my) + (o.y > my) + (o.z > my) + (o.w > my);
    }
    int t4 = t >> 2;
    for (int j4 = 0; j4 < t4; j4++) {
        float4 o = s4p[j4];
        rank += (o.x == my) + (o.y == my) + (o.z == my) + (o.w == my);
    }
    for (int j = t4 * 4; j < t; j++) rank += (s[j] == my);

    bool kept = rank < KPG;
    // rank8: kept -> score-rank (0..127), else 255.  coalesced byte store.
    rank8[g * NPG + t] = kept ? (unsigned char)rank : (unsigned char)255;
    if (kept) {
        int node = g * NPG + t;
        int nid  = g * KPG + rank;
        sel[rank]  = t;
        selw[rank] = my;
        out[OUT_BATCH + nid] = (float)g;
        out[OUT_PERM + nid]  = (float)node;
        out[OUT_W + nid]     = my;
    }
    __syncthreads();
    // gather + scale from L2/L3-warm x; NT output stores
    #pragma unroll
    for (int it = 0; it < KPG / 8; it++) {
        int r = it * 8 + grp;
        int node = g * NPG + sel[r];
        float wvs = selw[r];
        const vf4* sp = (const vf4*)(x + (size_t)node * DF);
        vf4 v = sp[l32];
        v *= wvs;
        __builtin_nontemporal_store(v,
            (vf4*)(out + OUT_X + ((size_t)g * KPG + r) * DF) + l32);
    }
}

// --- 2. map + stage: ei ONCE (NT), rank8 byte-gathers, LDS-dense pk/kl ---
__global__ void __launch_bounds__(SBLK)
mapstage_kernel(const int* __restrict__ ei,
                const unsigned char* __restrict__ rank8,
                unsigned* __restrict__ pk_ws,
                unsigned short* __restrict__ kl_ws,
                int* __restrict__ tilecounts) {
    int tile = blockIdx.x, t = threadIdx.x;
    int wave = t >> 6, lane = t & 63;
    __shared__ int wtot[4];
    __shared__ unsigned       s_pk[EPB];   // 4KB
    __shared__ unsigned short s_kl[EPB];   // 2KB

    int ebase = tile * EPB + t * 4;
    vi4 sv = __builtin_nontemporal_load((const vi4*)(ei + ebase));
    vi4 dv = __builtin_nontemporal_load((const vi4*)(ei + NE + ebase));
    int s4[4] = {sv.x, sv.y, sv.z, sv.w};
    int d4[4] = {dv.x, dv.y, dv.z, dv.w};
    unsigned rs[4], rd[4];
    #pragma unroll
    for (int j = 0; j < 4; j++) {
        rs[j] = rank8[(unsigned)s4[j]];
        rd[j] = rank8[(unsigned)d4[j]];
    }
    unsigned bits = 0;
    #pragma unroll
    for (int j = 0; j < 4; j++)
        bits |= ((rs[j] < 128u) & (rd[j] < 128u)) << j;
    int c = __popc(bits);
    // block exclusive scan of c
    int inc = c;
    #pragma unroll
    for (int off = 1; off < 64; off <<= 1) {
        int u = __shfl_up(inc, off, 64);
        if (lane >= off) inc += u;
    }
    if (lane == 63) wtot[wave] = inc;
    __syncthreads();
    int wbase = 0;
    #pragma unroll
    for (int i = 0; i < 4; i++) if (i < wave) wbase += wtot[i];
    int pre = wbase + inc - c;

    if (bits) {
        #pragma unroll
        for (int j = 0; j < 4; j++) {
            if ((bits >> j) & 1u) {
                unsigned ns = ((unsigned)s4[j] >> 8) * KPG + rs[j];
                unsigned nd = ((unsigned)d4[j] >> 8) * KPG + rd[j];
                s_pk[pre] = (ns << 16) | nd;
                s_kl[pre] = (unsigned short)(t * 4 + j);
                pre++;
            }
        }
    }
    __syncthreads();
    int cnt = wtot[0] + wtot[1] + wtot[2] + wtot[3];
    // coalesced flush (plain stores: consumed by scatter from L2)
    for (int j = t; j < cnt; j += SBLK) {
        pk_ws[tile * EPB + j] = s_pk[j];
        kl_ws[tile * EPB + j] = s_kl[j];
    }
    if (t == 0) tilecounts[tile] = cnt;
}

// --- 3. LDS-staged self-scan scatter + fused tail fill (NT out) ----------
__global__ void __launch_bounds__(SBLK)
scatter_kernel(const float* __restrict__ eattr,
               const unsigned* __restrict__ pk_ws,
               const unsigned short* __restrict__ kl_ws,
               const int* __restrict__ tilecounts,
               float* __restrict__ out) {
    int tile = blockIdx.x, t = threadIdx.x;
    int wave = t >> 6, lane = t & 63;
    __shared__ int warr[4];
    __shared__ int s_excl;
    __shared__ unsigned       s_pk[EPB];   // 4KB
    __shared__ unsigned short s_kl[EPB];   // 2KB

    int cnt = tilecounts[tile];
    // coalesced LDS staging of pk/kl (overlaps self-scan)
    for (int j = t; j < cnt; j += SBLK) {
        s_pk[j] = pk_ws[tile * EPB + j];
        s_kl[j] = kl_ws[tile * EPB + j];
    }
    // self-scan: excl = sum of tilecounts[0..tile)
    int partial = 0;
    for (int i = t; i < tile; i += SBLK) partial += tilecounts[i];
    #pragma unroll
    for (int off = 32; off > 0; off >>= 1) partial += __shfl_down(partial, off, 64);
    if (lane == 0) warr[wave] = partial;
    __syncthreads();
    if (t == 0) s_excl = warr[0] + warr[1] + warr[2] + warr[3];
    __syncthreads();
    int excl = s_excl;

    // dense new_ei writes (pk from LDS)
    for (int j = t; j < cnt; j += SBLK) {
        unsigned p = s_pk[j];
        __builtin_nontemporal_store((float)(p >> 16),     &out[OUT_EI + excl + j]);
        __builtin_nontemporal_store((float)(p & 0xFFFFu), &out[OUT_EI + NE + excl + j]);
    }
    // dense attr copy: 4 lanes per edge (64B row); kl from LDS (broadcast)
    int sub = t & 3;
    for (int j = t >> 2; j < cnt; j += SBLK / 4) {
        int el = s_kl[j];
        const vf4* sp = (const vf4*)(eattr + ((size_t)tile * EPB + el) * DE);
        vf4 v = __builtin_nontemporal_load(sp + sub);
        vf4* dp = (vf4*)(out + OUT_ATTR + ((size_t)excl + j) * DE);
        __builtin_nontemporal_store(v, dp + sub);
    }
    // fused tail fill: this tile's discarded edges own tail slots
    int disc_excl = tile * EPB - excl;
    int disc = EPB - cnt;
    size_t tail_lo = (size_t)NE - disc_excl - disc;
    for (int i = t; i < disc; i += SBLK) {
        __builtin_nontemporal_store(-1.f, &out[OUT_EI + tail_lo + i]);
        __builtin_nontemporal_store(-1.f, &out[OUT_EI + NE + tail_lo + i]);
    }
    vf4* ap = (vf4*)(out + OUT_ATTR);
    vf4 z = (vf4){0.f, 0.f, 0.f, 0.f};
    for (int i = t; i < disc * 4; i += SBLK)
        __builtin_nontemporal_store(z, &ap[tail_lo * 4 + i]);
}

extern "C" void kernel_launch(void* const* d_in, const int* in_sizes, int n_in,
                              void* d_out, int out_size, void* d_ws, size_t ws_size,
                              hipStream_t stream) {
    const float* x     = (const float*)d_in[0];
    const int*   ei    = (const int*)d_in[1];
    const float* eattr = (const float*)d_in[2];
    const float* W     = (const float*)d_in[4];
    const float* b     = (const float*)d_in[5];
    float* out = (float*)d_out;

    // workspace layout (~25.4 MB)
    unsigned char*  rank8      = (unsigned char*)d_ws;
    int*            tilecounts = (int*)(rank8 + NN);
    unsigned*       pk_ws      = (unsigned*)(tilecounts + NTILE);
    unsigned short* kl_ws      = (unsigned short*)(pk_ws + NE);

    topk_all_kernel<<<NGRAPH, NPG, 0, stream>>>(x, W, b, rank8, out);
    mapstage_kernel<<<NTILE, SBLK, 0, stream>>>(ei, rank8, pk_ws, kl_ws, tilecounts);
    scatter_kernel <<<NTILE, SBLK, 0, stream>>>(eattr, pk_ws, kl_ws, tilecounts, out);
}

// Round 17
// 146.322 us; speedup vs baseline: 1.0742x; 1.0742x over previous
//
#include <hip/hip_runtime.h>

#define NGRAPH 512
#define NPG    256
#define KPG    128
#define NN     (NGRAPH * NPG)   // 131072 nodes
#define KK     (NGRAPH * KPG)   // 65536 kept nodes
#define NE     4194304          // edges
#define DF     128
#define DE     16

#define SBLK   256              // threads per edge block
#define EPB    1024             // edges per tile (4 per thread)
#define NTILE  (NE / EPB)       // 4096 tiles

typedef float vf4 __attribute__((ext_vector_type(4)));
typedef int   vi4 __attribute__((ext_vector_type(4)));

// output layout (float32 elements, concatenated in reference return order)
#define OUT_X     0ull
#define OUT_EI    ((size_t)KK * DF)                 // 8388608
#define OUT_ATTR  (OUT_EI + 2ull * NE)              // 16777216
#define OUT_BATCH (OUT_ATTR + (size_t)NE * DE)      // 83886080
#define OUT_PERM  (OUT_BATCH + KK)
#define OUT_W     (OUT_PERM + KK)

// --- 1. fused score + top-k + gather-scale + node_map + kept bits --------
__global__ void __launch_bounds__(NPG)
topk_all_kernel(const float* __restrict__ x,
                const float* __restrict__ W,
                const float* __restrict__ b,
                int* __restrict__ node_map,
                unsigned* __restrict__ nkbits,
                float* __restrict__ out) {
    __shared__ __align__(16) float s[NPG];
    __shared__ int   sel[KPG];      // rank -> local node id
    __shared__ float selw[KPG];     // rank -> score
    int g = blockIdx.x, t = threadIdx.x;
    int wave = t >> 6, lane = t & 63;
    int l32 = t & 31, grp = t >> 5;
    float bias = b[0];

    // scores: 8 rows in flight (32 lanes x float4), 32 iters covers 256 rows
    float4 wv = ((const float4*)W)[l32];
    #pragma unroll 4
    for (int it = 0; it < NPG / 8; it++) {
        int r = it * 8 + grp;
        float4 xv = ((const float4*)(x + ((size_t)g * NPG + r) * DF))[l32];
        float sum = xv.x * wv.x + xv.y * wv.y + xv.z * wv.z + xv.w * wv.w;
        #pragma unroll
        for (int off = 16; off > 0; off >>= 1) sum += __shfl_down(sum, off, 32);
        if (l32 == 0) s[r] = sum + bias;
    }
    __syncthreads();
    float my = s[t];
    // rank = #{j: s[j] > my} + #{j < t: s[j] == my}
    const float4* s4p = (const float4*)s;
    int rank = 0;
    #pragma unroll 8
    for (int j4 = 0; j4 < NPG / 4; j4++) {
        float4 o = s4p[j4];
        rank += (o.x > my) + (o.y > my) + (o.z > my) + (o.w > my);
    }
    int t4 = t >> 2;
    for (int j4 = 0; j4 < t4; j4++) {
        float4 o = s4p[j4];
        rank += (o.x == my) + (o.y == my) + (o.z == my) + (o.w == my);
    }
    for (int j = t4 * 4; j < t; j++) rank += (s[j] == my);

    bool kept = rank < KPG;
    if (kept) {
        int node = g * NPG + t;
        int nid  = g * KPG + rank;
        node_map[node] = nid;
        sel[rank]  = t;
        selw[rank] = my;
        out[OUT_BATCH + nid] = (float)g;
        out[OUT_PERM + nid]  = (float)node;
        out[OUT_W + nid]     = my;
    }
    // node-kept bitmap: word (g*8 + t/32), bit (t&31)
    unsigned long long bal = __ballot(kept);
    if (lane == 0)  nkbits[g * 8 + wave * 2]     = (unsigned)bal;
    if (lane == 32) nkbits[g * 8 + wave * 2 + 1] = (unsigned)(bal >> 32);
    __syncthreads();
    // gather + scale from L2/L3-warm x; NT output stores
    #pragma unroll
    for (int it = 0; it < KPG / 8; it++) {
        int r = it * 8 + grp;
        int node = g * NPG + sel[r];
        float wvs = selw[r];
        const vf4* sp = (const vf4*)(x + (size_t)node * DF);
        vf4 v = sp[l32];
        v *= wvs;
        __builtin_nontemporal_store(v,
            (vf4*)(out + OUT_X + ((size_t)g * KPG + r) * DF) + l32);
    }
}

// --- 2. map + stage: read ei ONCE (NT), LDS-dense pk/kl, coalesced flush --
__global__ void __launch_bounds__(SBLK)
mapstage_kernel(const int* __restrict__ ei,
                const int* __restrict__ node_map,
                const unsigned* __restrict__ nkbits,
                unsigned* __restrict__ pk_ws,
                unsigned short* __restrict__ kl_ws,
                int* __restrict__ tilecounts) {
    int tile = blockIdx.x, t = threadIdx.x;
    int wave = t >> 6, lane = t & 63;
    __shared__ int wtot[4];
    __shared__ unsigned       s_pk[EPB];   // 4KB
    __shared__ unsigned short s_kl[EPB];   // 2KB

    int ebase = tile * EPB + t * 4;
    vi4 sv = __builtin_nontemporal_load((const vi4*)(ei + ebase));
    vi4 dv = __builtin_nontemporal_load((const vi4*)(ei + NE + ebase));
    #define KB(n) ((nkbits[(unsigned)(n) >> 5] >> ((unsigned)(n) & 31u)) & 1u)
    unsigned bits = (KB(sv.x) & KB(dv.x))
                  | ((KB(sv.y) & KB(dv.y)) << 1)
                  | ((KB(sv.z) & KB(dv.z)) << 2)
                  | ((KB(sv.w) & KB(dv.w)) << 3);
    #undef KB
    int c = __popc(bits);
    // block exclusive scan of c
    int inc = c;
    #pragma unroll
    for (int off = 1; off < 64; off <<= 1) {
        int u = __shfl_up(inc, off, 64);
        if (lane >= off) inc += u;
    }
    if (lane == 63) wtot[wave] = inc;
    __syncthreads();
    int wbase = 0;
    #pragma unroll
    for (int i = 0; i < 4; i++) if (i < wave) wbase += wtot[i];
    int pre = wbase + inc - c;

    if (bits) {
        int s4[4] = {sv.x, sv.y, sv.z, sv.w};
        int d4[4] = {dv.x, dv.y, dv.z, dv.w};
        #pragma unroll
        for (int j = 0; j < 4; j++) {
            if ((bits >> j) & 1u) {
                unsigned ns = (unsigned)node_map[s4[j]];
                unsigned nd = (unsigned)node_map[d4[j]];
                s_pk[pre] = (ns << 16) | nd;
                s_kl[pre] = (unsigned short)(t * 4 + j);
                pre++;
            }
        }
    }
    __syncthreads();
    int cnt = wtot[0] + wtot[1] + wtot[2] + wtot[3];
    // coalesced flush (plain stores: consumed by scatter from L2)
    for (int j = t; j < cnt; j += SBLK) {
        pk_ws[tile * EPB + j] = s_pk[j];
        kl_ws[tile * EPB + j] = s_kl[j];
    }
    if (t == 0) tilecounts[tile] = cnt;
}

// --- 3. LDS-staged self-scan scatter + fused tail fill (NT out) ----------
__global__ void __launch_bounds__(SBLK)
scatter_kernel(const float* __restrict__ eattr,
               const unsigned* __restrict__ pk_ws,
               const unsigned short* __restrict__ kl_ws,
               const int* __restrict__ tilecounts,
               float* __restrict__ out) {
    int tile = blockIdx.x, t = threadIdx.x;
    int wave = t >> 6, lane = t & 63;
    __shared__ int warr[4];
    __shared__ int s_excl;
    __shared__ unsigned       s_pk[EPB];   // 4KB
    __shared__ unsigned short s_kl[EPB];   // 2KB

    int cnt = tilecounts[tile];
    // coalesced LDS staging of pk/kl (overlaps self-scan)
    for (int j = t; j < cnt; j += SBLK) {
        s_pk[j] = pk_ws[tile * EPB + j];
        s_kl[j] = kl_ws[tile * EPB + j];
    }
    // self-scan: excl = sum of tilecounts[0..tile)
    int partial = 0;
    for (int i = t; i < tile; i += SBLK) partial += tilecounts[i];
    #pragma unroll
    for (int off = 32; off > 0; off >>= 1) partial += __shfl_down(partial, off, 64);
    if (lane == 0) warr[wave] = partial;
    __syncthreads();
    if (t == 0) s_excl = warr[0] + warr[1] + warr[2] + warr[3];
    __syncthreads();
    int excl = s_excl;

    // dense new_ei writes (pk from LDS)
    for (int j = t; j < cnt; j += SBLK) {
        unsigned p = s_pk[j];
        __builtin_nontemporal_store((float)(p >> 16),     &out[OUT_EI + excl + j]);
        __builtin_nontemporal_store((float)(p & 0xFFFFu), &out[OUT_EI + NE + excl + j]);
    }
    // dense attr copy: 4 lanes per edge (64B row); kl from LDS (broadcast)
    int sub = t & 3;
    for (int j = t >> 2; j < cnt; j += SBLK / 4) {
        int el = s_kl[j];
        const vf4* sp = (const vf4*)(eattr + ((size_t)tile * EPB + el) * DE);
        vf4 v = __builtin_nontemporal_load(sp + sub);
        vf4* dp = (vf4*)(out + OUT_ATTR + ((size_t)excl + j) * DE);
        __builtin_nontemporal_store(v, dp + sub);
    }
    // fused tail fill: this tile's discarded edges own tail slots
    int disc_excl = tile * EPB - excl;
    int disc = EPB - cnt;
    size_t tail_lo = (size_t)NE - disc_excl - disc;
    for (int i = t; i < disc; i += SBLK) {
        __builtin_nontemporal_store(-1.f, &out[OUT_EI + tail_lo + i]);
        __builtin_nontemporal_store(-1.f, &out[OUT_EI + NE + tail_lo + i]);
    }
    vf4* ap = (vf4*)(out + OUT_ATTR);
    vf4 z = (vf4){0.f, 0.f, 0.f, 0.f};
    for (int i = t; i < disc * 4; i += SBLK)
        __builtin_nontemporal_store(z, &ap[tail_lo * 4 + i]);
}

extern "C" void kernel_launch(void* const* d_in, const int* in_sizes, int n_in,
                              void* d_out, int out_size, void* d_ws, size_t ws_size,
                              hipStream_t stream) {
    const float* x     = (const float*)d_in[0];
    const int*   ei    = (const int*)d_in[1];
    const float* eattr = (const float*)d_in[2];
    const float* W     = (const float*)d_in[4];
    const float* b     = (const float*)d_in[5];
    float* out = (float*)d_out;

    // workspace layout (~26 MB)
    int*            node_map   = (int*)d_ws;
    unsigned*       nkbits     = (unsigned*)(node_map + NN);
    int*            tilecounts = (int*)(nkbits + NN / 32);
    unsigned*       pk_ws      = (unsigned*)(tilecounts + NTILE);
    unsigned short* kl_ws      = (unsigned short*)(pk_ws + NE);

    topk_all_kernel<<<NGRAPH, NPG, 0, stream>>>(x, W, b, node_map, nkbits, out);
    mapstage_kernel<<<NTILE, SBLK, 0, stream>>>(ei, node_map, nkbits, pk_ws, kl_ws, tilecounts);
    scatter_kernel <<<NTILE, SBLK, 0, stream>>>(eattr, pk_ws, kl_ws, tilecounts, out);
}